// Round 9
// baseline (144.670 us; speedup 1.0000x reference)
//
#include <hip/hip_runtime.h>

#define B_ 64
#define L_ 1024
#define M_ 256
#define F_ 256

typedef __attribute__((ext_vector_type(8))) short short8;    // 8 bf16 (4 VGPR)
typedef __attribute__((ext_vector_type(16))) float f32x16;   // 32x32 MFMA C/D
typedef unsigned int u32;

struct Frag3 { short8 h, m, l; };

__device__ __forceinline__ u32 asu(float f) { union { float f; u32 u; } c; c.f = f; return c.u; }
__device__ __forceinline__ float asf(u32 u) { union { float f; u32 u; } c; c.u = u; return c.f; }
__device__ __forceinline__ u32 pack2(u32 lo, u32 hi) {
    return __builtin_amdgcn_perm(hi, lo, 0x07060302u);
}
__device__ __forceinline__ float4 ld4(const float* p) {
    return *reinterpret_cast<const float4*>(p);
}

// Exact 3-way bf16 truncation split of 8 fp32: x = h + m + l (top 24 mantissa bits).
__device__ __forceinline__ Frag3 split8(float4 a, float4 b) {
    float x[8] = {a.x, a.y, a.z, a.w, b.x, b.y, b.z, b.w};
    u32 xb[8], rb[8], sb[8];
#pragma unroll
    for (int e = 0; e < 8; ++e) {
        xb[e] = asu(x[e]);
        float hf = asf(xb[e] & 0xFFFF0000u);
        float r  = x[e] - hf;                 // exact
        rb[e] = asu(r);
        float mf = asf(rb[e] & 0xFFFF0000u);
        float r2 = r - mf;                    // exact
        sb[e] = asu(r2);
    }
    union { u32 w[4]; short8 s; } H, M, Lo;
#pragma unroll
    for (int d = 0; d < 4; ++d) {
        H.w[d]  = pack2(xb[2 * d], xb[2 * d + 1]);
        M.w[d]  = pack2(rb[2 * d], rb[2 * d + 1]);
        Lo.w[d] = pack2(sb[2 * d], sb[2 * d + 1]);
    }
    Frag3 f; f.h = H.s; f.m = M.s; f.l = Lo.s; return f;
}

#define MFMA6(ACC, A, Bf)                                                        \
    ACC = __builtin_amdgcn_mfma_f32_32x32x16_bf16((A).m, (Bf).m, ACC, 0, 0, 0);  \
    ACC = __builtin_amdgcn_mfma_f32_32x32x16_bf16((A).h, (Bf).l, ACC, 0, 0, 0);  \
    ACC = __builtin_amdgcn_mfma_f32_32x32x16_bf16((A).l, (Bf).h, ACC, 0, 0, 0);  \
    ACC = __builtin_amdgcn_mfma_f32_32x32x16_bf16((A).h, (Bf).m, ACC, 0, 0, 0);  \
    ACC = __builtin_amdgcn_mfma_f32_32x32x16_bf16((A).m, (Bf).h, ACC, 0, 0, 0);  \
    ACC = __builtin_amdgcn_mfma_f32_32x32x16_bf16((A).h, (Bf).h, ACC, 0, 0, 0)

// Loads for one k-step into a named 6-float4 buffer (ping-pong, no arrays ->
// all-static indexing, rule #20).
#define LOADK(KK, A0, A1, B00, B01, B10, B11)                    \
    {                                                            \
        const float* ap_ = Abase + (KK) * 16;                    \
        const float* bp_ = Bbase + (KK) * 16;                    \
        A0  = ld4(ap_);                                          \
        A1  = ld4(ap_ + 4);                                      \
        B00 = ld4(bp_);                                          \
        B01 = ld4(bp_ + 4);                                      \
        B10 = ld4(bp_ + (size_t)32 * F_);                        \
        B11 = ld4(bp_ + (size_t)32 * F_ + 4);                    \
    }

#define BODY(A0, A1, B00, B01, B10, B11)                         \
    {                                                            \
        const Frag3 A  = split8(A0, A1);                         \
        const Frag3 Bf0 = split8(B00, B01);                      \
        MFMA6(acc0, A, Bf0);                                     \
        const Frag3 Bf1 = split8(B10, B11);                      \
        MFMA6(acc1, A, Bf1);                                     \
    }

// One block per l, 512 threads = 8 waves. Wave (bt=w&1, mtg=w>>1):
// b-rows bt*32..+31, m-cols mtg*64..+63 (2 m-tiles of 32).
// Register ping-pong: k-step kk+1's 6 loads issue before kk's split+MFMA.
// D layout: col(m)=lane&31, row=(reg&3)+8*(reg>>2)+4*(lane>>5)  [m74/m101].
__launch_bounds__(512, 2)
__global__ void mq_mfma32_kernel(const float* __restrict__ patch,
                                 const float* __restrict__ queue,
                                 float* __restrict__ out) {
    const int l    = blockIdx.x;
    const int t    = threadIdx.x;
    const int lane = t & 63;
    const int w    = t >> 6;        // 0..7
    const int bt   = w & 1;
    const int mtg  = w >> 1;        // 0..3
    const int r32  = lane & 31;
    const int kh   = lane >> 5;     // k-half: f-offset kh*8

    __shared__ float pval[4][64];
    __shared__ int   pidx[4][64];
    __shared__ int   sidx[64];

    f32x16 acc0 = (f32x16)0.f, acc1 = (f32x16)0.f;

    const float* Abase = patch + ((size_t)(bt * 32 + r32) * L_ + l) * F_ + kh * 8;
    const float* Bbase = queue + ((size_t)l * M_ + mtg * 64 + r32) * F_ + kh * 8;

    float4 xA0, xA1, xB00, xB01, xB10, xB11;   // buffer X
    float4 yA0, yA1, yB00, yB01, yB10, yB11;   // buffer Y

    LOADK(0, xA0, xA1, xB00, xB01, xB10, xB11);

#pragma unroll 1
    for (int kk2 = 0; kk2 < 8; ++kk2) {
        // even step: compute from X, prefetch odd step into Y
        LOADK(2 * kk2 + 1, yA0, yA1, yB00, yB01, yB10, yB11);
        BODY(xA0, xA1, xB00, xB01, xB10, xB11);
        // odd step: compute from Y, prefetch next even step into X
        if (kk2 < 7) {
            LOADK(2 * kk2 + 2, xA0, xA1, xB00, xB01, xB10, xB11);
        }
        BODY(yA0, yA1, yB00, yB01, yB10, yB11);
    }

    // Per-wave argmax over its 64 m-cols for each of its 32 b-rows.
    // In-lane mt ascending (m ascending) + strict '>' keeps lowest m;
    // 32-lane butterfly prefers lower idx on tie (numpy first-occurrence).
#pragma unroll
    for (int r = 0; r < 16; ++r) {
        float bv = acc0[r];
        int   bi = mtg * 64 + r32;
        {
            const float cv = acc1[r];
            const int   ci = mtg * 64 + 32 + r32;
            if (cv > bv) { bv = cv; bi = ci; }
        }
#pragma unroll
        for (int off = 16; off >= 1; off >>= 1) {
            const float ov = __shfl_xor(bv, off);
            const int   oi = __shfl_xor(bi, off);
            if (ov > bv || (ov == bv && oi < bi)) { bv = ov; bi = oi; }
        }
        if (r32 == 0) {
            const int b = bt * 32 + (r & 3) + 8 * (r >> 2) + 4 * kh;
            pval[mtg][b] = bv;
            pidx[mtg][b] = bi;
        }
    }
    __syncthreads();

    // Combine the four m-quarters; ascending mtg with strict '>' keeps the
    // lowest m on ties -> numpy first-occurrence.
    if (t < 64) {
        float bv = pval[0][t];
        int   bi = pidx[0][t];
#pragma unroll
        for (int g = 1; g < 4; ++g) {
            const float cv = pval[g][t];
            if (cv > bv) { bv = cv; bi = pidx[g][t]; }
        }
        sidx[t] = bi;
    }
    __syncthreads();

    // gather: out[b][l][:] = queue[l][sidx[b]][:]  (queue[l] is L2-hot)
    const int cb = t >> 6;     // 0..7
    const int cc = t & 63;     // float4 index within the 256-float row
#pragma unroll
    for (int b0 = 0; b0 < 64; b0 += 8) {
        const int b  = b0 + cb;
        const int mi = sidx[b];
        const float4 v = ld4(&queue[((size_t)l * M_ + mi) * F_ + cc * 4]);
        *reinterpret_cast<float4*>(&out[((size_t)b * L_ + l) * F_ + cc * 4]) = v;
    }
}

extern "C" void kernel_launch(void* const* d_in, const int* in_sizes, int n_in,
                              void* d_out, int out_size, void* d_ws, size_t ws_size,
                              hipStream_t stream) {
    const float* patch = (const float*)d_in[0];
    const float* queue = (const float*)d_in[1];
    float* out = (float*)d_out;
    mq_mfma32_kernel<<<dim3(L_), dim3(512), 0, stream>>>(patch, queue, out);
}

// Round 10
// 106.741 us; speedup vs baseline: 1.3553x; 1.3553x over previous
//
#include <hip/hip_runtime.h>

#define B_ 64
#define L_ 1024
#define M_ 256
#define F_ 256

typedef __attribute__((ext_vector_type(8))) short short8;    // 8 bf16 (4 VGPR)
typedef __attribute__((ext_vector_type(16))) float f32x16;   // 32x32 MFMA C/D
typedef unsigned int u32;

struct Frag3 { short8 h, m, l; };

__device__ __forceinline__ u32 asu(float f) { union { float f; u32 u; } c; c.f = f; return c.u; }
__device__ __forceinline__ float asf(u32 u) { union { float f; u32 u; } c; c.u = u; return c.f; }
__device__ __forceinline__ u32 pack2(u32 lo, u32 hi) {
    return __builtin_amdgcn_perm(hi, lo, 0x07060302u);
}
__device__ __forceinline__ float4 ld4(const float* p) {
    return *reinterpret_cast<const float4*>(p);
}

// Async 16B global->LDS DMA; LDS dest wave-uniform, per-lane source carries
// the XOR swizzle (m173 pattern, validated R6).
__device__ __forceinline__ void async_cp16(const float* g, float* l) {
    __builtin_amdgcn_global_load_lds(
        (const __attribute__((address_space(1))) u32*)g,
        (__attribute__((address_space(3))) u32*)l,
        16, 0, 0);
}

// Exact 3-way bf16 truncation split of 8 fp32: x = h + m + l (top 24 mantissa bits).
__device__ __forceinline__ Frag3 split8(float4 a, float4 b) {
    float x[8] = {a.x, a.y, a.z, a.w, b.x, b.y, b.z, b.w};
    u32 xb[8], rb[8], sb[8];
#pragma unroll
    for (int e = 0; e < 8; ++e) {
        xb[e] = asu(x[e]);
        float hf = asf(xb[e] & 0xFFFF0000u);
        float r  = x[e] - hf;                 // exact
        rb[e] = asu(r);
        float mf = asf(rb[e] & 0xFFFF0000u);
        float r2 = r - mf;                    // exact
        sb[e] = asu(r2);
    }
    union { u32 w[4]; short8 s; } H, M, Lo;
#pragma unroll
    for (int d = 0; d < 4; ++d) {
        H.w[d]  = pack2(xb[2 * d], xb[2 * d + 1]);
        M.w[d]  = pack2(rb[2 * d], rb[2 * d + 1]);
        Lo.w[d] = pack2(sb[2 * d], sb[2 * d + 1]);
    }
    Frag3 f; f.h = H.s; f.m = M.s; f.l = Lo.s; return f;
}

#define MFMA6(ACC, A, Bf)                                                        \
    ACC = __builtin_amdgcn_mfma_f32_32x32x16_bf16((A).m, (Bf).m, ACC, 0, 0, 0);  \
    ACC = __builtin_amdgcn_mfma_f32_32x32x16_bf16((A).h, (Bf).l, ACC, 0, 0, 0);  \
    ACC = __builtin_amdgcn_mfma_f32_32x32x16_bf16((A).l, (Bf).h, ACC, 0, 0, 0);  \
    ACC = __builtin_amdgcn_mfma_f32_32x32x16_bf16((A).h, (Bf).m, ACC, 0, 0, 0);  \
    ACC = __builtin_amdgcn_mfma_f32_32x32x16_bf16((A).m, (Bf).h, ACC, 0, 0, 0);  \
    ACC = __builtin_amdgcn_mfma_f32_32x32x16_bf16((A).h, (Bf).h, ACC, 0, 0, 0)

// One block per l, 256 threads = 4 waves. Wave (bt=w&1, mtg=w>>1):
// b-rows bt*32..+31, m-cols mtg*128..+127. K tiled by 32 f, double-buffered
// LDS staged via global_load_lds (DMA issued right after the barrier -> in
// flight across the whole previous-tile compute). Rows stored with 16B-chunk
// slot = chunk ^ (row&7) (pre-swizzled at the source), read back with the
// same XOR -> conflict-free b128 fragment reads.
// D layout: col(m)=lane&31, row=(reg&3)+8*(reg>>2)+4*(lane>>5)  [m74/m101].
__launch_bounds__(256, 2)
__global__ void mq_mfma_lds_kernel(const float* __restrict__ patch,
                                   const float* __restrict__ queue,
                                   float* __restrict__ out) {
    const int l    = blockIdx.x;
    const int t    = threadIdx.x;
    const int lane = t & 63;
    const int w    = t >> 6;        // 0..3
    const int bt   = w & 1;
    const int mtg  = w >> 1;        // 0..1
    const int r32  = lane & 31;
    const int kh   = lane >> 5;     // k-half: f-offset kh*8

    __shared__ __align__(16) float Ql[2][256 * 32];  // 2 x 32KB
    __shared__ __align__(16) float Pl[2][64 * 32];   // 2 x 8KB   (total 80KB)

    // ---- staging geometry (R6 pattern; swizzle now on both Q and P) ----
    const int lrow = lane >> 3;     // 0..7: row within an 8-row chunk-group
    const int lcol = lane & 7;      // 0..7: 16B slot within a 128B row
    // Lane (lrow,lcol) lands at slot lcol of row g*8+lrow; we want slot s to
    // hold chunk s^(row&7), so the source chunk is lcol ^ lrow.
    const float* qsrcw = queue + ((size_t)l * M_ + w * 64 + lrow) * F_ + (lcol ^ lrow) * 4;
    const float* psrcw = patch + ((size_t)(w * 16 + lrow) * L_ + l) * F_ + (lcol ^ lrow) * 4;

#define STAGE(FT, BUF)                                                            \
    {                                                                             \
        _Pragma("unroll")                                                         \
        for (int k = 0; k < 8; ++k)                                               \
            async_cp16(qsrcw + (size_t)k * 8 * F_ + (FT) * 32,                    \
                       &Ql[BUF][(w * 8 + k) * 256]);                              \
        _Pragma("unroll")                                                         \
        for (int k = 0; k < 2; ++k)                                               \
            async_cp16(psrcw + (size_t)k * 8 * L_ * F_ + (FT) * 32,               \
                       &Pl[BUF][(w * 2 + k) * 256]);                              \
    }

    f32x16 acc[4];
#pragma unroll
    for (int mt = 0; mt < 4; ++mt) acc[mt] = (f32x16)0.f;

    STAGE(0, 0);

    const int s7 = r32 & 7;          // read-side XOR (rb&7 == r32&7 for all tiles)
    const int ra = bt * 32 + r32;    // P row for this lane

#pragma unroll 1
    for (int ft = 0; ft < 8; ++ft) {
        __syncthreads();   // implicit vmcnt(0): tile ft landed; buf ft^1 free
        if (ft < 7) STAGE(ft + 1, (ft + 1) & 1);

        const float* Qb = Ql[ft & 1];
        const float* Pb = Pl[ft & 1];
#pragma unroll
        for (int kk = 0; kk < 2; ++kk) {
            const int c0 = kk * 4 + kh * 2;   // first 16B chunk of this fragment
            const float4 a0 = ld4(&Pb[ra * 32 + ((c0 ^ s7) * 4)]);
            const float4 a1 = ld4(&Pb[ra * 32 + (((c0 + 1) ^ s7) * 4)]);
            const Frag3 A = split8(a0, a1);
#pragma unroll
            for (int mt = 0; mt < 4; ++mt) {
                const int rb = mtg * 128 + mt * 32 + r32;
                const float4 b0 = ld4(&Qb[rb * 32 + ((c0 ^ s7) * 4)]);
                const float4 b1 = ld4(&Qb[rb * 32 + (((c0 + 1) ^ s7) * 4)]);
                const Frag3 Bf = split8(b0, b1);
                MFMA6(acc[mt], A, Bf);
            }
        }
    }

    // argmax over m per b (numpy first-occurrence; same logic as R8).
    // Scratch overlays Pl[0]: dead since the ft=7 barrier (ft=7 uses buf 1).
    float* pval = (float*)&Pl[0][0];          // [2][64]
    int*   pidx = (int*)&Pl[0][0] + 128;      // [2][64]
    int*   sidx = (int*)&Pl[0][0] + 256;      // [64]
#pragma unroll
    for (int r = 0; r < 16; ++r) {
        float bv = acc[0][r];
        int   bi = mtg * 128 + r32;
#pragma unroll
        for (int mt = 1; mt < 4; ++mt) {
            const float cv = acc[mt][r];
            const int   ci = mtg * 128 + mt * 32 + r32;
            if (cv > bv) { bv = cv; bi = ci; }
        }
#pragma unroll
        for (int off = 16; off >= 1; off >>= 1) {
            const float ov = __shfl_xor(bv, off);
            const int   oi = __shfl_xor(bi, off);
            if (ov > bv || (ov == bv && oi < bi)) { bv = ov; bi = oi; }
        }
        if (r32 == 0) {
            const int b = bt * 32 + (r & 3) + 8 * (r >> 2) + 4 * kh;
            pval[mtg * 64 + b] = bv;
            pidx[mtg * 64 + b] = bi;
        }
    }
    __syncthreads();

    // Combine the two m-halves; mtg0 (lower m) wins ties -> first occurrence.
    if (t < 64) {
        const float v0 = pval[t], v1 = pval[64 + t];
        sidx[t] = (v1 > v0) ? pidx[64 + t] : pidx[t];
    }
    __syncthreads();

    // gather: out[b][l][:] = queue[l][sidx[b]][:]  (queue[l] is L2-hot)
    const int cb = t >> 6;     // 0..3
    const int cc = t & 63;     // float4 index within the 256-float row
#pragma unroll
    for (int b0 = 0; b0 < 64; b0 += 4) {
        const int b  = b0 + cb;
        const int mi = sidx[b];
        const float4 v = ld4(&queue[((size_t)l * M_ + mi) * F_ + cc * 4]);
        *reinterpret_cast<float4*>(&out[((size_t)b * L_ + l) * F_ + cc * 4]) = v;
    }
}

extern "C" void kernel_launch(void* const* d_in, const int* in_sizes, int n_in,
                              void* d_out, int out_size, void* d_ws, size_t ws_size,
                              hipStream_t stream) {
    const float* patch = (const float*)d_in[0];
    const float* queue = (const float*)d_in[1];
    float* out = (float*)d_out;
    mq_mfma_lds_kernel<<<dim3(L_), dim3(256), 0, stream>>>(patch, queue, out);
}

// Round 11
// 105.927 us; speedup vs baseline: 1.3657x; 1.0077x over previous
//
#include <hip/hip_runtime.h>

#define B_ 64
#define L_ 1024
#define M_ 256
#define F_ 256

typedef __attribute__((ext_vector_type(8))) short short8;    // 8 bf16 (4 VGPR)
typedef __attribute__((ext_vector_type(16))) float f32x16;   // 32x32 MFMA C/D
typedef unsigned int u32;

struct Frag3 { short8 h, m, l; };

__device__ __forceinline__ u32 asu(float f) { union { float f; u32 u; } c; c.f = f; return c.u; }
__device__ __forceinline__ float asf(u32 u) { union { float f; u32 u; } c; c.u = u; return c.f; }
__device__ __forceinline__ u32 pack2(u32 lo, u32 hi) {
    return __builtin_amdgcn_perm(hi, lo, 0x07060302u);
}
__device__ __forceinline__ float4 ld4(const float* p) {
    return *reinterpret_cast<const float4*>(p);
}

// Async 16B global->LDS DMA; LDS dest wave-uniform, per-lane source carries
// the XOR swizzle (m173 pattern, validated R6/R10).
__device__ __forceinline__ void async_cp16(const float* g, float* l) {
    __builtin_amdgcn_global_load_lds(
        (const __attribute__((address_space(1))) u32*)g,
        (__attribute__((address_space(3))) u32*)l,
        16, 0, 0);
}

// Exact 3-way bf16 truncation split of 8 fp32: x = h + m + l (top 24 mantissa bits).
__device__ __forceinline__ Frag3 split8(float4 a, float4 b) {
    float x[8] = {a.x, a.y, a.z, a.w, b.x, b.y, b.z, b.w};
    u32 xb[8], rb[8], sb[8];
#pragma unroll
    for (int e = 0; e < 8; ++e) {
        xb[e] = asu(x[e]);
        float hf = asf(xb[e] & 0xFFFF0000u);
        float r  = x[e] - hf;                 // exact
        rb[e] = asu(r);
        float mf = asf(rb[e] & 0xFFFF0000u);
        float r2 = r - mf;                    // exact
        sb[e] = asu(r2);
    }
    union { u32 w[4]; short8 s; } H, M, Lo;
#pragma unroll
    for (int d = 0; d < 4; ++d) {
        H.w[d]  = pack2(xb[2 * d], xb[2 * d + 1]);
        M.w[d]  = pack2(rb[2 * d], rb[2 * d + 1]);
        Lo.w[d] = pack2(sb[2 * d], sb[2 * d + 1]);
    }
    Frag3 f; f.h = H.s; f.m = M.s; f.l = Lo.s; return f;
}

#define MFMA6(ACC, A, Bf)                                                        \
    ACC = __builtin_amdgcn_mfma_f32_32x32x16_bf16((A).m, (Bf).m, ACC, 0, 0, 0);  \
    ACC = __builtin_amdgcn_mfma_f32_32x32x16_bf16((A).h, (Bf).l, ACC, 0, 0, 0);  \
    ACC = __builtin_amdgcn_mfma_f32_32x32x16_bf16((A).l, (Bf).h, ACC, 0, 0, 0);  \
    ACC = __builtin_amdgcn_mfma_f32_32x32x16_bf16((A).h, (Bf).m, ACC, 0, 0, 0);  \
    ACC = __builtin_amdgcn_mfma_f32_32x32x16_bf16((A).m, (Bf).h, ACC, 0, 0, 0);  \
    ACC = __builtin_amdgcn_mfma_f32_32x32x16_bf16((A).h, (Bf).h, ACC, 0, 0, 0)

// One block per l, 256 threads = 4 waves. Wave (bt=w&1, mtg=w>>1):
// b-rows bt*32..+31, m-cols mtg*128..+127. K tiled by 32 f, LDS dbuf staged
// by global_load_lds. T3/T4: raw s_barrier pairs + counted vmcnt(10) -- the
// block's DMA stream NEVER drains to 0 in the main loop, so HBM stays fed.
//   barrier#1: all waves done reading buf[(ft+1)&1]  -> safe to overwrite
//   STAGE(ft+1): 10 cp16/wave into that buffer
//   s_waitcnt vmcnt(10): own tile-ft chunks (oldest 10) retired
//   barrier#2: every wave's tile-ft chunks landed    -> safe to read
// D layout: col(m)=lane&31, row=(reg&3)+8*(reg>>2)+4*(lane>>5)  [m74/m101].
__launch_bounds__(256, 2)
__global__ void mq_mfma_lds_kernel(const float* __restrict__ patch,
                                   const float* __restrict__ queue,
                                   float* __restrict__ out) {
    const int l    = blockIdx.x;
    const int t    = threadIdx.x;
    const int lane = t & 63;
    const int w    = t >> 6;        // 0..3
    const int bt   = w & 1;
    const int mtg  = w >> 1;        // 0..1
    const int r32  = lane & 31;
    const int kh   = lane >> 5;     // k-half: f-offset kh*8

    __shared__ __align__(16) float Ql[2][256 * 32];  // 2 x 32KB
    __shared__ __align__(16) float Pl[2][64 * 32];   // 2 x 8KB   (total 80KB)

    // ---- staging geometry (R6/R10 pattern; swizzle on both Q and P) ----
    const int lrow = lane >> 3;     // 0..7: row within an 8-row chunk-group
    const int lcol = lane & 7;      // 0..7: 16B slot within a 128B row
    const float* qsrcw = queue + ((size_t)l * M_ + w * 64 + lrow) * F_ + (lcol ^ lrow) * 4;
    const float* psrcw = patch + ((size_t)(w * 16 + lrow) * L_ + l) * F_ + (lcol ^ lrow) * 4;

#define STAGE(FT, BUF)                                                            \
    {                                                                             \
        _Pragma("unroll")                                                         \
        for (int k = 0; k < 8; ++k)                                               \
            async_cp16(qsrcw + (size_t)k * 8 * F_ + (FT) * 32,                    \
                       &Ql[BUF][(w * 8 + k) * 256]);                              \
        _Pragma("unroll")                                                         \
        for (int k = 0; k < 2; ++k)                                               \
            async_cp16(psrcw + (size_t)k * 8 * L_ * F_ + (FT) * 32,               \
                       &Pl[BUF][(w * 2 + k) * 256]);                              \
    }

    f32x16 acc[4];
#pragma unroll
    for (int mt = 0; mt < 4; ++mt) acc[mt] = (f32x16)0.f;

    STAGE(0, 0);

    const int s7 = r32 & 7;          // read-side XOR (rb&7 == r32&7 for all tiles)
    const int ra = bt * 32 + r32;    // P row for this lane

#pragma unroll 1
    for (int ft = 0; ft < 8; ++ft) {
        // barrier#1: all waves finished reading buf[(ft+1)&1] (tile ft-1).
        __builtin_amdgcn_s_barrier();
        __builtin_amdgcn_sched_barrier(0);
        if (ft < 7) {
            STAGE(ft + 1, (ft + 1) & 1);
            // own tile-ft chunks (oldest 10 of 20 outstanding) retired;
            // tile ft+1's 10 stay in flight across the whole compute phase.
            asm volatile("s_waitcnt vmcnt(10)" ::: "memory");
        } else {
            asm volatile("s_waitcnt vmcnt(0)" ::: "memory");
        }
        __builtin_amdgcn_sched_barrier(0);
        // barrier#2: every wave's tile-ft chunks have landed.
        __builtin_amdgcn_s_barrier();
        __builtin_amdgcn_sched_barrier(0);

        const float* Qb = Ql[ft & 1];
        const float* Pb = Pl[ft & 1];
#pragma unroll
        for (int kk = 0; kk < 2; ++kk) {
            const int c0 = kk * 4 + kh * 2;   // first 16B chunk of this fragment
            const float4 a0 = ld4(&Pb[ra * 32 + ((c0 ^ s7) * 4)]);
            const float4 a1 = ld4(&Pb[ra * 32 + (((c0 + 1) ^ s7) * 4)]);
            const Frag3 A = split8(a0, a1);
#pragma unroll
            for (int mt = 0; mt < 4; ++mt) {
                const int rb = mtg * 128 + mt * 32 + r32;
                const float4 b0 = ld4(&Qb[rb * 32 + ((c0 ^ s7) * 4)]);
                const float4 b1 = ld4(&Qb[rb * 32 + (((c0 + 1) ^ s7) * 4)]);
                const Frag3 Bf = split8(b0, b1);
                MFMA6(acc[mt], A, Bf);
            }
        }
    }

    __syncthreads();   // full drain before scratch overlays Pl[0]

    // argmax over m per b (numpy first-occurrence; same logic as R8/R10).
    float* pval = (float*)&Pl[0][0];          // [2][64]
    int*   pidx = (int*)&Pl[0][0] + 128;      // [2][64]
    int*   sidx = (int*)&Pl[0][0] + 256;      // [64]
#pragma unroll
    for (int r = 0; r < 16; ++r) {
        float bv = acc[0][r];
        int   bi = mtg * 128 + r32;
#pragma unroll
        for (int mt = 1; mt < 4; ++mt) {
            const float cv = acc[mt][r];
            const int   ci = mtg * 128 + mt * 32 + r32;
            if (cv > bv) { bv = cv; bi = ci; }
        }
#pragma unroll
        for (int off = 16; off >= 1; off >>= 1) {
            const float ov = __shfl_xor(bv, off);
            const int   oi = __shfl_xor(bi, off);
            if (ov > bv || (ov == bv && oi < bi)) { bv = ov; bi = oi; }
        }
        if (r32 == 0) {
            const int b = bt * 32 + (r & 3) + 8 * (r >> 2) + 4 * kh;
            pval[mtg * 64 + b] = bv;
            pidx[mtg * 64 + b] = bi;
        }
    }
    __syncthreads();

    // Combine the two m-halves; mtg0 (lower m) wins ties -> first occurrence.
    if (t < 64) {
        const float v0 = pval[t], v1 = pval[64 + t];
        sidx[t] = (v1 > v0) ? pidx[64 + t] : pidx[t];
    }
    __syncthreads();

    // gather: out[b][l][:] = queue[l][sidx[b]][:]  (queue[l] is L2-hot)
    const int cb = t >> 6;     // 0..3
    const int cc = t & 63;     // float4 index within the 256-float row
#pragma unroll
    for (int b0 = 0; b0 < 64; b0 += 4) {
        const int b  = b0 + cb;
        const int mi = sidx[b];
        const float4 v = ld4(&queue[((size_t)l * M_ + mi) * F_ + cc * 4]);
        *reinterpret_cast<float4*>(&out[((size_t)b * L_ + l) * F_ + cc * 4]) = v;
    }
}

extern "C" void kernel_launch(void* const* d_in, const int* in_sizes, int n_in,
                              void* d_out, int out_size, void* d_ws, size_t ws_size,
                              hipStream_t stream) {
    const float* patch = (const float*)d_in[0];
    const float* queue = (const float*)d_in[1];
    float* out = (float*)d_out;
    mq_mfma_lds_kernel<<<dim3(L_), dim3(256), 0, stream>>>(patch, queue, out);
}

// Round 13
// 103.511 us; speedup vs baseline: 1.3976x; 1.0233x over previous
//
#include <hip/hip_runtime.h>

#define B_ 64
#define L_ 1024
#define M_ 256
#define F_ 256

typedef __attribute__((ext_vector_type(8))) short short8;    // 8 bf16 (4 VGPR)
typedef __attribute__((ext_vector_type(16))) float f32x16;   // 32x32 MFMA C/D
typedef unsigned int u32;

struct Frag3 { short8 h, m, l; };

__device__ __forceinline__ u32 asu(float f) { union { float f; u32 u; } c; c.f = f; return c.u; }
__device__ __forceinline__ float asf(u32 u) { union { float f; u32 u; } c; c.u = u; return c.f; }
__device__ __forceinline__ u32 pack2(u32 lo, u32 hi) {
    return __builtin_amdgcn_perm(hi, lo, 0x07060302u);
}
__device__ __forceinline__ float4 ld4(const float* p) {
    return *reinterpret_cast<const float4*>(p);
}

// Async 16B global->LDS DMA; LDS dest wave-uniform, per-lane source carries
// the XOR swizzle (m173 pattern, validated R6/R10).
__device__ __forceinline__ void async_cp16(const float* g, float* l) {
    __builtin_amdgcn_global_load_lds(
        (const __attribute__((address_space(1))) u32*)g,
        (__attribute__((address_space(3))) u32*)l,
        16, 0, 0);
}

// Exact 3-way bf16 truncation split of 8 fp32: x = h + m + l (top 24 mantissa bits).
__device__ __forceinline__ Frag3 split8(float4 a, float4 b) {
    float x[8] = {a.x, a.y, a.z, a.w, b.x, b.y, b.z, b.w};
    u32 xb[8], rb[8], sb[8];
#pragma unroll
    for (int e = 0; e < 8; ++e) {
        xb[e] = asu(x[e]);
        float hf = asf(xb[e] & 0xFFFF0000u);
        float r  = x[e] - hf;                 // exact
        rb[e] = asu(r);
        float mf = asf(rb[e] & 0xFFFF0000u);
        float r2 = r - mf;                    // exact
        sb[e] = asu(r2);
    }
    union { u32 w[4]; short8 s; } H, M, Lo;
#pragma unroll
    for (int d = 0; d < 4; ++d) {
        H.w[d]  = pack2(xb[2 * d], xb[2 * d + 1]);
        M.w[d]  = pack2(rb[2 * d], rb[2 * d + 1]);
        Lo.w[d] = pack2(sb[2 * d], sb[2 * d + 1]);
    }
    Frag3 f; f.h = H.s; f.m = M.s; f.l = Lo.s; return f;
}

#define MFMA6(ACC, A, Bf)                                                        \
    ACC = __builtin_amdgcn_mfma_f32_32x32x16_bf16((A).m, (Bf).m, ACC, 0, 0, 0);  \
    ACC = __builtin_amdgcn_mfma_f32_32x32x16_bf16((A).h, (Bf).l, ACC, 0, 0, 0);  \
    ACC = __builtin_amdgcn_mfma_f32_32x32x16_bf16((A).l, (Bf).h, ACC, 0, 0, 0);  \
    ACC = __builtin_amdgcn_mfma_f32_32x32x16_bf16((A).h, (Bf).m, ACC, 0, 0, 0);  \
    ACC = __builtin_amdgcn_mfma_f32_32x32x16_bf16((A).m, (Bf).h, ACC, 0, 0, 0);  \
    ACC = __builtin_amdgcn_mfma_f32_32x32x16_bf16((A).h, (Bf).h, ACC, 0, 0, 0)

// One block per l, 512 threads = 8 waves -> 2 blocks/CU = 4 waves/SIMD (2x R11's
// latency hiding). Wave (bt=w&1, mtg=w>>1): b-rows bt*32..+31, m-cols
// mtg*64..+63. K tiled by 32 f, LDS dbuf staged by global_load_lds with raw
// s_barrier pairs + counted vmcnt(5) (each wave stages 5 chunks/tile).
// D layout: col(m)=lane&31, row=(reg&3)+8*(reg>>2)+4*(lane>>5)  [m74/m101].
__launch_bounds__(512, 2)
__global__ void mq_mfma_lds_kernel(const float* __restrict__ patch,
                                   const float* __restrict__ queue,
                                   float* __restrict__ out) {
    const int l    = blockIdx.x;
    const int t    = threadIdx.x;
    const int lane = t & 63;
    const int w    = t >> 6;        // 0..7
    const int bt   = w & 1;
    const int mtg  = w >> 1;        // 0..3
    const int r32  = lane & 31;
    const int kh   = lane >> 5;     // k-half: f-offset kh*8

    __shared__ __align__(16) float Ql[2][256 * 32];  // 2 x 32KB
    __shared__ __align__(16) float Pl[2][64 * 32];   // 2 x 8KB   (total 80KB)

    // ---- staging geometry: wave w stages Q rows w*32..w*32+31 (4 chunks)
    //      and P rows w*8..w*8+7 (1 chunk); swizzled source chunk lcol^lrow.
    const int lrow = lane >> 3;     // 0..7: row within an 8-row chunk
    const int lcol = lane & 7;      // 0..7: 16B slot within a 128B row
    const float* qsrcw = queue + ((size_t)l * M_ + w * 32 + lrow) * F_ + (lcol ^ lrow) * 4;
    const float* psrcw = patch + ((size_t)(w * 8 + lrow) * L_ + l) * F_ + (lcol ^ lrow) * 4;

#define STAGE(FT, BUF)                                                            \
    {                                                                             \
        _Pragma("unroll")                                                         \
        for (int k = 0; k < 4; ++k)                                               \
            async_cp16(qsrcw + (size_t)k * 8 * F_ + (FT) * 32,                    \
                       &Ql[BUF][(w * 4 + k) * 256]);                              \
        async_cp16(psrcw + (FT) * 32, &Pl[BUF][w * 256]);                         \
    }

    f32x16 acc0 = (f32x16)0.f, acc1 = (f32x16)0.f;

    STAGE(0, 0);

    const int s7 = r32 & 7;          // read-side XOR (row&7 == r32&7 everywhere)
    const int ra = bt * 32 + r32;    // P row for this lane
    const int rb0 = mtg * 64 + r32;  // first Q row
    const int rb1 = mtg * 64 + 32 + r32;

#pragma unroll 1
    for (int ft = 0; ft < 8; ++ft) {
        // barrier#1: all waves finished reading buf[(ft+1)&1] (tile ft-1).
        __builtin_amdgcn_s_barrier();
        __builtin_amdgcn_sched_barrier(0);
        if (ft < 7) {
            STAGE(ft + 1, (ft + 1) & 1);
            // own tile-ft chunks (oldest 5 of 10 outstanding) retired;
            // tile ft+1's 5 stay in flight across the whole compute phase.
            asm volatile("s_waitcnt vmcnt(5)" ::: "memory");
        } else {
            asm volatile("s_waitcnt vmcnt(0)" ::: "memory");
        }
        __builtin_amdgcn_sched_barrier(0);
        // barrier#2: every wave's tile-ft chunks have landed.
        __builtin_amdgcn_s_barrier();
        __builtin_amdgcn_sched_barrier(0);

        const float* Qb = Ql[ft & 1];
        const float* Pb = Pl[ft & 1];
#pragma unroll
        for (int kk = 0; kk < 2; ++kk) {
            const int c0 = kk * 4 + kh * 2;   // first 16B chunk of this fragment
            const float4 a0 = ld4(&Pb[ra * 32 + ((c0 ^ s7) * 4)]);
            const float4 a1 = ld4(&Pb[ra * 32 + (((c0 + 1) ^ s7) * 4)]);
            const Frag3 A = split8(a0, a1);
            {
                const float4 b0 = ld4(&Qb[rb0 * 32 + ((c0 ^ s7) * 4)]);
                const float4 b1 = ld4(&Qb[rb0 * 32 + (((c0 + 1) ^ s7) * 4)]);
                const Frag3 Bf = split8(b0, b1);
                MFMA6(acc0, A, Bf);
            }
            {
                const float4 b0 = ld4(&Qb[rb1 * 32 + ((c0 ^ s7) * 4)]);
                const float4 b1 = ld4(&Qb[rb1 * 32 + (((c0 + 1) ^ s7) * 4)]);
                const Frag3 Bf = split8(b0, b1);
                MFMA6(acc1, A, Bf);
            }
        }
    }

    __syncthreads();   // full drain before scratch overlays Pl[0]

    // argmax over m per b (numpy first-occurrence). Wave partials over its
    // 64 cols; in-lane acc0->acc1 ascending m, strict '>' keeps lowest m.
    float* pval = (float*)&Pl[0][0];          // [4][64]
    int*   pidx = (int*)&Pl[0][0] + 256;      // [4][64]
    int*   sidx = (int*)&Pl[0][0] + 512;      // [64]
#pragma unroll
    for (int r = 0; r < 16; ++r) {
        float bv = acc0[r];
        int   bi = mtg * 64 + r32;
        {
            const float cv = acc1[r];
            const int   ci = mtg * 64 + 32 + r32;
            if (cv > bv) { bv = cv; bi = ci; }
        }
#pragma unroll
        for (int off = 16; off >= 1; off >>= 1) {
            const float ov = __shfl_xor(bv, off);
            const int   oi = __shfl_xor(bi, off);
            if (ov > bv || (ov == bv && oi < bi)) { bv = ov; bi = oi; }
        }
        if (r32 == 0) {
            const int b = bt * 32 + (r & 3) + 8 * (r >> 2) + 4 * kh;
            pval[mtg * 64 + b] = bv;
            pidx[mtg * 64 + b] = bi;
        }
    }
    __syncthreads();

    // Combine the four m-quarters; ascending mtg with strict '>' keeps the
    // lowest m on ties -> numpy first-occurrence.
    if (t < 64) {
        float bv = pval[t];
        int   bi = pidx[t];
#pragma unroll
        for (int g = 1; g < 4; ++g) {
            const float cv = pval[g * 64 + t];
            if (cv > bv) { bv = cv; bi = pidx[g * 64 + t]; }
        }
        sidx[t] = bi;
    }
    __syncthreads();

    // gather: out[b][l][:] = queue[l][sidx[b]][:]  (queue[l] is L2-hot)
    const int cb = t >> 6;     // 0..7
    const int cc = t & 63;     // float4 index within the 256-float row
#pragma unroll
    for (int b0 = 0; b0 < 64; b0 += 8) {
        const int b  = b0 + cb;
        const int mi = sidx[b];
        const float4 v = ld4(&queue[((size_t)l * M_ + mi) * F_ + cc * 4]);
        *reinterpret_cast<float4*>(&out[((size_t)b * L_ + l) * F_ + cc * 4]) = v;
    }
}

extern "C" void kernel_launch(void* const* d_in, const int* in_sizes, int n_in,
                              void* d_out, int out_size, void* d_ws, size_t ws_size,
                              hipStream_t stream) {
    const float* patch = (const float*)d_in[0];
    const float* queue = (const float*)d_in[1];
    float* out = (float*)d_out;
    mq_mfma_lds_kernel<<<dim3(L_), dim3(512), 0, stream>>>(patch, queue, out);
}